// Round 10
// baseline (113.952 us; speedup 1.0000x reference)
//
#include <hip/hip_runtime.h>
#include <hip/hip_bf16.h>

#define D_DIM 256
#define K_CODES 1024
#define N_ROWS (32 * 1024)
#define BLOCK_ROWS 128                // rows per main block (4 waves x 32)
#define NRG (N_ROWS / BLOCK_ROWS)     // 256 row-groups
#define NCY 4                         // code quarters (256 codes each)
#define NBLK (NRG * NCY)              // 1024 main blocks
#define STEPS 8                       // 32-code tiles per quarter
#define TILE_SH 8256                  // shorts: 16KB frags + 128B enorm
#define NGB 512                       // gather blocks (64 rows each)

typedef __attribute__((ext_vector_type(8))) short bf16x8;
typedef __attribute__((ext_vector_type(4))) float f32x4;

#define MFMA16 __builtin_amdgcn_mfma_f32_16x16x32_bf16

static __device__ __forceinline__ short f2bf(float f) {
    __hip_bfloat16 h = __float2bfloat16(f);   // RNE
    return *reinterpret_cast<short*>(&h);
}

static __device__ __forceinline__ bf16x8 pack8(float4 a, float4 b) {
    bf16x8 r;
    r[0] = f2bf(a.x); r[1] = f2bf(a.y); r[2] = f2bf(a.z); r[3] = f2bf(a.w);
    r[4] = f2bf(b.x); r[5] = f2bf(b.y); r[6] = f2bf(b.z); r[7] = f2bf(b.w);
    return r;
}

static __device__ __forceinline__ void gload_lds16(const void* g, void* s) {
    __builtin_amdgcn_global_load_lds(
        (const __attribute__((address_space(1))) void*)g,
        (__attribute__((address_space(3))) void*)s, 16, 0, 0);
}
static __device__ __forceinline__ void gload_lds4(const void* g, void* s) {
    __builtin_amdgcn_global_load_lds(
        (const __attribute__((address_space(1))) void*)g,
        (__attribute__((address_space(3))) void*)s, 4, 0, 0);
}

// ---------------------------------------------------------------- prep
// (a) enorm[k] = ||E[k]||^2; (b) Eb = bf16(-2*E), MFMA B-fragment order:
// frag g = t*512 + kk*64 + l holds E[code = t*16 + (l&15)][d = kk*32 + (l>>4)*8 ..+8]
__global__ __launch_bounds__(256) void vq_prep(const float* __restrict__ E,
                                               float* __restrict__ enorm,
                                               short* __restrict__ Eb) {
    int wave = threadIdx.x >> 6;
    int lane = threadIdx.x & 63;
    int k = blockIdx.x * 4 + wave;               // [0,1024)
    const float4 v = *reinterpret_cast<const float4*>(E + k * D_DIM + lane * 4);
    float s = v.x * v.x + v.y * v.y + v.z * v.z + v.w * v.w;
    #pragma unroll
    for (int off = 32; off; off >>= 1) s += __shfl_xor(s, off, 64);
    if (lane == 0) enorm[k] = s;

    if (blockIdx.x < 128) {
        int g = blockIdx.x * 256 + threadIdx.x;  // [0, 32768)
        int t = g >> 9;
        int kk = (g >> 6) & 7;
        int l = g & 63;
        int code = t * 16 + (l & 15);
        int d = kk * 32 + ((l >> 4) << 3);
        const float* src = E + (size_t)code * D_DIM + d;
        float4 v0 = *reinterpret_cast<const float4*>(src);
        float4 v1 = *reinterpret_cast<const float4*>(src + 4);
        v0.x *= -2.f; v0.y *= -2.f; v0.z *= -2.f; v0.w *= -2.f;
        v1.x *= -2.f; v1.y *= -2.f; v1.z *= -2.f; v1.w *= -2.f;
        *reinterpret_cast<bf16x8*>(Eb + (size_t)g * 8) = pack8(v0, v1);
    }
}

// ---------------------------------------------------------------- main
// bid = rowgroup*4 + cy. Block: 128 rows x 256 codes (quarter cy).
// 4 waves rg0..3, each 32 rows x ALL 256 codes -> per step (32-code tile,
// 16KB, ring-3, vmcnt(5)+s_barrier): 2 codesets x 16 = 32 MFMA/wave =
// 2.1 MFLOP/block-step (m97 density). Rows are wave-private -> no merge.
// Writes (minval,idx) pairs per (row, cy) + xnorm (for the loss identity
// |x-q|^2 = minval + |x|^2); gather kernel does the rest.
__global__ __launch_bounds__(256, 3) void vq_main(const float* __restrict__ X,
                                                  const float* __restrict__ enorm,
                                                  const short* __restrict__ Eb,
                                                  float2* __restrict__ pairs,
                                                  float* __restrict__ xnorm) {
    __shared__ short lds[3][TILE_SH];   // 49.5 KB

    const int tid  = threadIdx.x;
    const int rg   = tid >> 6;    // wave = row group (32 rows)
    const int l    = tid & 63;
    const int lr   = l & 15;      // A row-in-16 / B,C code col
    const int lk   = l >> 4;
    const int cy    = blockIdx.x & 3;            // code quarter
    const int brow0 = (blockIdx.x >> 2) * BLOCK_ROWS;
    const int row0  = brow0 + rg * 32;

    // 5 uniform loads per wave per stage: 4 frag chunks + 8 enorm floats
#define STAGE(TT, BUF)                                                        \
    do {                                                                      \
        const int tg_ = cy * STEPS + (TT);        /* global 32-code tile */   \
        _Pragma("unroll")                                                     \
        for (int kv = 0; kv < 4; ++kv) {                                      \
            const int f = rg * 256 + kv * 64;     /* uniform frag base */     \
            gload_lds16(Eb + ((size_t)tg_ * 1024 + f + l) * 8,                \
                        &lds[BUF][f * 8]);                                    \
        }                                                                     \
        if (l < 8) gload_lds4(enorm + tg_ * 32 + rg * 8 + l,                  \
                              &lds[BUF][8192 + rg * 16]);                     \
    } while (0)

    STAGE(0, 0);
    STAGE(1, 1);

    // ---- prologue: 32 rows of X -> bf16 A-frags + f32 row norms
    bf16x8 a[2][8];
    float  xn[2] = {0.f, 0.f};
    #pragma unroll
    for (int s = 0; s < 2; ++s) {
        const float* xp = X + (size_t)(row0 + s * 16 + lr) * D_DIM + lk * 8;
        #pragma unroll
        for (int kk = 0; kk < 8; ++kk) {
            float4 p = *reinterpret_cast<const float4*>(xp + kk * 32);
            float4 q = *reinterpret_cast<const float4*>(xp + kk * 32 + 4);
            a[s][kk] = pack8(p, q);
            xn[s] += p.x * p.x + p.y * p.y + p.z * p.z + p.w * p.w
                   + q.x * q.x + q.y * q.y + q.z * q.z + q.w * q.w;
        }
    }
    #pragma unroll
    for (int s = 0; s < 2; ++s) {
        xn[s] += __shfl_xor(xn[s], 16, 64);
        xn[s] += __shfl_xor(xn[s], 32, 64);
    }
    if (cy == 0 && l < 16) {
        xnorm[row0 + lr]      = xn[0];
        xnorm[row0 + 16 + lr] = xn[1];
    }

    float minv[2][4];
    int   mini[2][4];
    #pragma unroll
    for (int s = 0; s < 2; ++s)
        #pragma unroll
        for (int i = 0; i < 4; ++i) { minv[s][i] = INFINITY; mini[s][i] = 0; }

#define CSET(BUF, CS, TT)                                                     \
    do {                                                                      \
        bf16x8 b[8];                                                          \
        _Pragma("unroll")                                                     \
        for (int kk = 0; kk < 8; ++kk)                                        \
            b[kk] = *reinterpret_cast<const bf16x8*>(                         \
                &lds[BUF][(CS) * 4096 + kk * 512 + l * 8]);                   \
        const float en = *reinterpret_cast<const float*>(                     \
            &lds[BUF][8192 + (CS) * 32 + lr * 2]);                            \
        f32x4 acc0 = {0, 0, 0, 0}, acc1 = {0, 0, 0, 0};                       \
        _Pragma("unroll")                                                     \
        for (int kk = 0; kk < 8; ++kk) {                                      \
            acc0 = MFMA16(a[0][kk], b[kk], acc0, 0, 0, 0);                    \
            acc1 = MFMA16(a[1][kk], b[kk], acc1, 0, 0, 0);                    \
        }                                                                     \
        const int idx_ = cy * 256 + (TT) * 32 + (CS) * 16 + lr;               \
        _Pragma("unroll")                                                     \
        for (int i = 0; i < 4; ++i) {                                         \
            float s0 = acc0[i] + en;                                          \
            float s1 = acc1[i] + en;                                          \
            if (s0 < minv[0][i]) { minv[0][i] = s0; mini[0][i] = idx_; }      \
            if (s1 < minv[1][i]) { minv[1][i] = s1; mini[1][i] = idx_; }      \
        }                                                                     \
    } while (0)

#define STEP(TT, LAST)                                                        \
    do {                                                                      \
        const int buf_ = (TT) % 3;                                            \
        if (LAST) { asm volatile("s_waitcnt vmcnt(0)" ::: "memory"); }        \
        else      { asm volatile("s_waitcnt vmcnt(5)" ::: "memory"); }        \
        __builtin_amdgcn_sched_barrier(0);                                    \
        __builtin_amdgcn_s_barrier();                                         \
        if (!(LAST) && (TT) + 2 < STEPS) STAGE((TT) + 2, ((TT) + 2) % 3);     \
        CSET(buf_, 0, TT);                                                    \
        CSET(buf_, 1, TT);                                                    \
        __builtin_amdgcn_sched_barrier(0);                                    \
    } while (0)

    for (int tt = 0; tt < STEPS - 1; ++tt) STEP(tt, false);
    STEP(STEPS - 1, true);
#undef STEP
#undef CSET
#undef STAGE

    // ---- reduce over the 16 code-lanes (first-min tie-break)
    #pragma unroll
    for (int off = 8; off >= 1; off >>= 1) {
        #pragma unroll
        for (int s = 0; s < 2; ++s)
            #pragma unroll
            for (int i = 0; i < 4; ++i) {
                float ov = __shfl_xor(minv[s][i], off, 64);
                int   oi = __shfl_xor(mini[s][i], off, 64);
                if (ov < minv[s][i] || (ov == minv[s][i] && oi < mini[s][i])) {
                    minv[s][i] = ov; mini[s][i] = oi;
                }
            }
    }

    // lanes lr==0 (l = lk*16) hold rows rs*16 + lk*4 + i
    if (lr == 0) {
        #pragma unroll
        for (int s = 0; s < 2; ++s)
            #pragma unroll
            for (int i = 0; i < 4; ++i) {
                const int row = row0 + s * 16 + lk * 4 + i;
                float2 p; p.x = minv[s][i]; p.y = __int_as_float(mini[s][i]);
                pairs[(size_t)row * NCY + cy] = p;
            }
    }
}

// ---------------------------------------------------------------- gather
// Merge the 4 quarter partials per row, gather E[idx] -> outq, and
// accumulate loss via |x-q|^2 = minval + xnorm[row] (no X re-read).
__global__ __launch_bounds__(256) void vq_gather(const float* __restrict__ E,
                                                 const float2* __restrict__ pairs,
                                                 const float* __restrict__ xnorm,
                                                 float* __restrict__ outq,
                                                 float* __restrict__ loss_partial) {
    __shared__ float wsum[4];
    const int tid   = threadIdx.x;
    const int brow0 = blockIdx.x * 64;

    float lsum = 0.0f;
    #pragma unroll
    for (int h = 0; h < 2; ++h) {
        const int r   = h * 32 + (tid >> 3);
        const int c8  = tid & 7;
        const int row = brow0 + r;
        float2 best = pairs[(size_t)row * NCY + 0];
        #pragma unroll
        for (int c = 1; c < NCY; ++c) {
            float2 p = pairs[(size_t)row * NCY + c];
            // ascending quarters => strict < keeps first-occurrence min
            if (p.x < best.x ||
                (p.x == best.x && __float_as_int(p.y) < __float_as_int(best.y)))
                best = p;
        }
        const int idx = __float_as_int(best.y);
        if (c8 == 0) lsum += best.x + xnorm[row];
        const float* eq  = E + (size_t)idx * D_DIM;
        float*       orw = outq + (size_t)row * D_DIM;
        #pragma unroll
        for (int j = 0; j < 8; ++j) {
            int d = c8 * 4 + j * 32;
            float4 q = *reinterpret_cast<const float4*>(eq + d);
            f32x4 qv = {q.x, q.y, q.z, q.w};
            __builtin_nontemporal_store(qv, reinterpret_cast<f32x4*>(orw + d));
        }
    }
    #pragma unroll
    for (int off = 32; off; off >>= 1) lsum += __shfl_xor(lsum, off, 64);
    const int wave = tid >> 6, lane = tid & 63;
    if (lane == 0) wsum[wave] = lsum;
    __syncthreads();
    if (tid == 0)
        loss_partial[blockIdx.x] = wsum[0] + wsum[1] + wsum[2] + wsum[3];
}

// ---------------------------------------------------------------- finalize
// deterministic fold of 512 block partials -> vq_loss scalar
__global__ __launch_bounds__(256) void vq_finalize(const float* __restrict__ partials,
                                                   float* __restrict__ out_loss) {
    __shared__ float s[256];
    int t = threadIdx.x;
    s[t] = partials[t] + partials[t + 256];
    __syncthreads();
    #pragma unroll
    for (int off = 128; off; off >>= 1) {
        if (t < off) s[t] += s[t + off];
        __syncthreads();
    }
    if (t == 0)
        out_loss[0] = s[0] * (1.25f / (float)((size_t)N_ROWS * D_DIM));
}

// ---------------------------------------------------------------- launch
extern "C" void kernel_launch(void* const* d_in, const int* in_sizes, int n_in,
                              void* d_out, int out_size, void* d_ws, size_t ws_size,
                              hipStream_t stream) {
    const float* X = (const float*)d_in[0];   // latents  [32768, 256] f32
    const float* E = (const float*)d_in[1];   // codebook [1024, 256]  f32
    float* out = (float*)d_out;               // 8388608 quantized + 1 loss

    float*  enorm = (float*)d_ws;                         // 1024 f32
    float*  lpart = enorm + K_CODES;                      // 512 f32 (1024 slot)
    short*  Eb    = (short*)(lpart + 1024);               // 512 KB bf16
    float2* pairs = (float2*)(Eb + 32768 * 8);            // 1 MB
    float*  xnorm = (float*)(pairs + (size_t)N_ROWS * NCY); // 128 KB

    vq_prep    <<<256,  256, 0, stream>>>(E, enorm, Eb);
    vq_main    <<<NBLK, 256, 0, stream>>>(X, enorm, Eb, pairs, xnorm);
    vq_gather  <<<NGB,  256, 0, stream>>>(E, pairs, xnorm, out, lpart);
    vq_finalize<<<1,    256, 0, stream>>>(lpart, out + (size_t)N_ROWS * D_DIM);
}

// Round 11
// 41.169 us; speedup vs baseline: 2.7679x; 2.7679x over previous
//
#include <hip/hip_runtime.h>
#include <hip/hip_bf16.h>

#define D_DIM 256
#define K_CODES 1024
#define N_ROWS (32 * 1024)
#define BLOCK_ROWS 128                // rows per block (4 waves x 32)
#define NBLK (N_ROWS / BLOCK_ROWS)    // 256 blocks = 1/CU
#define QTILES 16                     // 16-code tiles per quarter
#define NQ 4                          // code quarters (256 codes each)

typedef __attribute__((ext_vector_type(4))) float f32x4;
typedef __attribute__((ext_vector_type(2))) long i64x2;
typedef long i64;

#define MFMA8 __builtin_amdgcn_mfma_f32_16x16x32_fp8_fp8
#define CVT8 __builtin_amdgcn_cvt_pk_fp8_f32

static __device__ __forceinline__ void gload_lds16(const void* g, void* s) {
    __builtin_amdgcn_global_load_lds(
        (const __attribute__((address_space(1))) void*)g,
        (__attribute__((address_space(3))) void*)s, 16, 0, 0);
}

static __device__ __forceinline__ i64 pack_fp8x8(float4 p, float4 q, float S) {
    int w0 = CVT8(p.x * S, p.y * S, 0, false);
    w0     = CVT8(p.z * S, p.w * S, w0, true);
    int w1 = CVT8(q.x * S, q.y * S, 0, false);
    w1     = CVT8(q.z * S, q.w * S, w1, true);
    return ((i64)(unsigned)w1 << 32) | (unsigned)w0;
}

// ---------------------------------------------------------------- prep
// (a) enorm[k] = ||E[k]||^2 (f32, exact E);
// (b) Eb8 = fp8(-1024*E) in MFMA B-frag order, kk-PAIRED for b128 reads:
//     i64 idx(tile,kk,l) = tile*512 + (kk>>1)*128 + l*2 + (kk&1)
//     holds E[code = tile*16 + (l&15)][d = kk*32 + (l>>4)*8 + j] at byte j.
__global__ __launch_bounds__(256) void vq_prep(const float* __restrict__ E,
                                               float* __restrict__ enorm,
                                               i64* __restrict__ Eb8) {
    int wave = threadIdx.x >> 6;
    int lane = threadIdx.x & 63;
    int k = blockIdx.x * 4 + wave;               // [0,1024)
    const float4 v = *reinterpret_cast<const float4*>(E + k * D_DIM + lane * 4);
    float s = v.x * v.x + v.y * v.y + v.z * v.z + v.w * v.w;
    #pragma unroll
    for (int off = 32; off; off >>= 1) s += __shfl_xor(s, off, 64);
    if (lane == 0) enorm[k] = s;

    if (blockIdx.x < 128) {
        int g = blockIdx.x * 256 + threadIdx.x;  // [0, 32768)
        int t = g >> 9;
        int kk = (g >> 6) & 7;
        int l = g & 63;
        int code = t * 16 + (l & 15);
        int d0 = kk * 32 + ((l >> 4) << 3);
        const float* src = E + (size_t)code * D_DIM + d0;
        float4 v0 = *reinterpret_cast<const float4*>(src);
        float4 v1 = *reinterpret_cast<const float4*>(src + 4);
        Eb8[t * 512 + ((kk >> 1) << 7) + l * 2 + (kk & 1)] =
            pack_fp8x8(v0, v1, -1024.0f);
    }
}

// ---------------------------------------------------------------- main
// 256 blocks (1/CU) x 256 thr. Block: 128 rows; wave w owns rows
// [w*32, w*32+32) vs ALL 1024 codes. X in registers as fp8 A-frags.
// Codebook swept in 4 quarters; quarter tiles (64 KB fp8) ping-pong in
// LDS, staged one FULL quarter ahead -> vmcnt(0) at quarter top is free;
// exactly 1 barrier per quarter. Fused epilogue: gather f32 E (output
// exact), loss via |x-q|^2 = minval + |x|^2.
__global__ __launch_bounds__(256, 1) void vq_main(const float* __restrict__ X,
                                                  const float* __restrict__ E,
                                                  const float* __restrict__ enorm,
                                                  const i64* __restrict__ Eb8,
                                                  float* __restrict__ outq,
                                                  float* __restrict__ lpart) {
    __shared__ i64   Bq[2][8192];   // 2 x 64 KB quarter buffers
    __shared__ float En[1024];      // 4 KB enorm
    __shared__ int   fidx[128];
    __shared__ float fmv[128];
    __shared__ float fxn[128];
    __shared__ float wsum[4];

    const int tid = threadIdx.x;
    const int w   = tid >> 6;
    const int l   = tid & 63;
    const int lr  = l & 15;
    const int lk  = l >> 4;
    const int row0 = blockIdx.x * BLOCK_ROWS + w * 32;

#define STAGEQ(Q, BUF)                                                        \
    do {                                                                      \
        _Pragma("unroll")                                                     \
        for (int it = 0; it < 16; ++it) {                                     \
            const int i = (it * 256 + tid) * 2;                               \
            gload_lds16(Eb8 + (size_t)(Q) * 8192 + i, &Bq[BUF][i]);           \
        }                                                                     \
    } while (0)

    // prologue staging: enorm + quarters 0,1
    gload_lds16(enorm + tid * 4, &En[tid * 4]);
    STAGEQ(0, 0);
    STAGEQ(1, 1);

    // ---- X -> fp8 A-frags (32 rows/wave, 2 rowsets) + f32 row norms
    i64  a[2][8];
    float xn[2] = {0.f, 0.f};
    #pragma unroll
    for (int s = 0; s < 2; ++s) {
        const float* xp = X + (size_t)(row0 + s * 16 + lr) * D_DIM + lk * 8;
        #pragma unroll
        for (int kk = 0; kk < 8; ++kk) {
            float4 p = *reinterpret_cast<const float4*>(xp + kk * 32);
            float4 q = *reinterpret_cast<const float4*>(xp + kk * 32 + 4);
            xn[s] += p.x * p.x + p.y * p.y + p.z * p.z + p.w * p.w
                   + q.x * q.x + q.y * q.y + q.z * q.z + q.w * q.w;
            a[s][kk] = pack_fp8x8(p, q, 1.0f);
        }
        xn[s] += __shfl_xor(xn[s], 16, 64);
        xn[s] += __shfl_xor(xn[s], 32, 64);   // all lanes: xnorm of row lr
    }

    float minv[2][4];
    int   mini[2][4];
    #pragma unroll
    for (int s = 0; s < 2; ++s)
        #pragma unroll
        for (int i = 0; i < 4; ++i) { minv[s][i] = INFINITY; mini[s][i] = 0; }

    const float inv = 1.0f / 512.0f;   // undo the -1024 scale (we want -2x.e)

    #pragma unroll
    for (int q = 0; q < NQ; ++q) {
        const int buf = q & 1;
        asm volatile("s_waitcnt vmcnt(0)" ::: "memory");   // quarter-old: free
        __builtin_amdgcn_sched_barrier(0);
        __builtin_amdgcn_s_barrier();
        if (q == 1 || q == 2) STAGEQ(q + 1, (q + 1) & 1);

        #pragma unroll 4
        for (int ct = 0; ct < QTILES; ++ct) {
            i64x2 bp[4];
            #pragma unroll
            for (int p = 0; p < 4; ++p)
                bp[p] = *reinterpret_cast<const i64x2*>(
                    &Bq[buf][ct * 512 + p * 128 + l * 2]);

            f32x4 acc0 = {0, 0, 0, 0}, acc1 = {0, 0, 0, 0};
            #pragma unroll
            for (int kk = 0; kk < 8; ++kk) {
                const i64 b = bp[kk >> 1][kk & 1];
                acc0 = MFMA8(a[0][kk], b, acc0, 0, 0, 0);
                acc1 = MFMA8(a[1][kk], b, acc1, 0, 0, 0);
            }

            const int gt  = q * QTILES + ct;
            const float en = En[gt * 16 + lr];
            const int idx = gt * 16 + lr;
            #pragma unroll
            for (int i = 0; i < 4; ++i) {
                float s0 = fmaf(acc0[i], inv, en);
                float s1 = fmaf(acc1[i], inv, en);
                if (s0 < minv[0][i]) { minv[0][i] = s0; mini[0][i] = idx; }
                if (s1 < minv[1][i]) { minv[1][i] = s1; mini[1][i] = idx; }
            }
        }
    }
#undef STAGEQ

    // ---- reduce over the 16 code-lanes (first-min tie-break, butterfly)
    #pragma unroll
    for (int off = 8; off >= 1; off >>= 1) {
        #pragma unroll
        for (int s = 0; s < 2; ++s)
            #pragma unroll
            for (int i = 0; i < 4; ++i) {
                float ov = __shfl_xor(minv[s][i], off, 64);
                int   oi = __shfl_xor(mini[s][i], off, 64);
                if (ov < minv[s][i] || (ov == minv[s][i] && oi < mini[s][i])) {
                    minv[s][i] = ov; mini[s][i] = oi;
                }
            }
    }

    // ---- publish per-wave results (wave-private region: no barrier needed)
    if (l < 16) { fxn[w * 32 + l] = xn[0]; fxn[w * 32 + 16 + l] = xn[1]; }
    if (lr == 0) {
        #pragma unroll
        for (int s = 0; s < 2; ++s)
            #pragma unroll
            for (int i = 0; i < 4; ++i) {
                const int rr = s * 16 + lk * 4 + i;
                fidx[w * 32 + rr] = mini[s][i];
                fmv[w * 32 + rr]  = minv[s][i];
            }
    }
    asm volatile("s_waitcnt lgkmcnt(0)" ::: "memory");
    __builtin_amdgcn_sched_barrier(0);

    // ---- fused gather: E[idx] (f32, exact) -> outq; 1 KB/row coalesced
    #pragma unroll 8
    for (int r = 0; r < 32; ++r) {
        const int bidx = fidx[w * 32 + r];
        const float4 qv = *reinterpret_cast<const float4*>(
            E + (size_t)bidx * D_DIM + l * 4);
        f32x4 t = {qv.x, qv.y, qv.z, qv.w};
        __builtin_nontemporal_store(
            t, reinterpret_cast<f32x4*>(outq + (size_t)(row0 + r) * D_DIM + l * 4));
    }

    // ---- loss: sum (minval + xnorm) over this wave's 32 rows
    float v = (l < 32) ? (fmv[w * 32 + l] + fxn[w * 32 + l]) : 0.0f;
    #pragma unroll
    for (int off = 32; off; off >>= 1) v += __shfl_xor(v, off, 64);
    if (l == 0) wsum[w] = v;
    __syncthreads();
    if (tid == 0)
        lpart[blockIdx.x] = wsum[0] + wsum[1] + wsum[2] + wsum[3];
}

// ---------------------------------------------------------------- finalize
// deterministic fold of 256 block partials -> vq_loss scalar
__global__ __launch_bounds__(256) void vq_finalize(const float* __restrict__ partials,
                                                   float* __restrict__ out_loss) {
    __shared__ float s[256];
    int t = threadIdx.x;
    s[t] = partials[t];
    __syncthreads();
    #pragma unroll
    for (int off = 128; off; off >>= 1) {
        if (t < off) s[t] += s[t + off];
        __syncthreads();
    }
    if (t == 0)
        out_loss[0] = s[0] * (1.25f / (float)((size_t)N_ROWS * D_DIM));
}

// ---------------------------------------------------------------- launch
extern "C" void kernel_launch(void* const* d_in, const int* in_sizes, int n_in,
                              void* d_out, int out_size, void* d_ws, size_t ws_size,
                              hipStream_t stream) {
    const float* X = (const float*)d_in[0];   // latents  [32768, 256] f32
    const float* E = (const float*)d_in[1];   // codebook [1024, 256]  f32
    float* out = (float*)d_out;               // 8388608 quantized + 1 loss

    float* enorm = (float*)d_ws;                          // 1024 f32
    float* lpart = enorm + K_CODES;                       // 256 f32 (1024 slot)
    i64*   Eb8   = (i64*)(lpart + 1024);                  // 256 KB fp8 frags

    vq_prep    <<<256,  256, 0, stream>>>(E, enorm, Eb8);
    vq_main    <<<NBLK, 256, 0, stream>>>(X, E, enorm, Eb8, out, lpart);
    vq_finalize<<<1,    256, 0, stream>>>(lpart, out + (size_t)N_ROWS * D_DIM);
}